// Round 9
// baseline (7992.705 us; speedup 1.0000x reference)
//
#include <hip/hip_runtime.h>
#include <hip/hip_bf16.h>

// R13 = R12 resubmit unchanged (round-8 bench failure = acquire-level
// "container failed twice" infra flake; identical signature to rounds 0/3/6,
// all of which passed on unchanged resubmit. k_att3 re-audited: uniform
// barriers, no hand-rolled vmcnt, bounds verified, static loops -> no
// hang/fault path. Changing code on an infra flake would conflate variables.)
// R12: kill the softmax kernel — fuse stats+exp into a restructured att.
//  - k_att3: grid (32,8). Block = 32 n-rows x ALL 512 c (acc[2][8]); S is
//    read once implicitly. In-block stats prologue (row max/inv-sum from G,
//    exp count 1x: rows partition blocks exactly). la staged from G f32 with
//    exp((g-m))*inv applied in f32 then bf16 (same rounding as old softmax).
//    lb = Ycn [512][32] via 4x proven DMA stage. XCD-homing bijection
//    x2=(bid&7)*4+(bid>>3) keeps G reads on the producing XCD.
//  - k_softmax deleted; 60 fewer launches; S write (16MB/inv) eliminated.
// R8: conv3 counted-vmcnt pipeline (MfmaUtil 46->61%). R6: LDS XOR swizzle.
// R5: global_load_lds staging. R4: persistent att outputs, conv3 z=48,
//  gru0+1 merged.

using bf16 = __hip_bfloat16;
typedef __attribute__((ext_vector_type(8))) short bf16x8;
typedef __attribute__((ext_vector_type(4))) float floatx4;

#define MFMA_BF16(a, b, c) __builtin_amdgcn_mfma_f32_16x16x32_bf16((a), (b), (c), 0, 0, 0)

// Async 16B global->LDS DMA. LDS dest must be wave-uniform base + lane*16.
__device__ __forceinline__ void gload_lds16(const bf16* g, bf16* l) {
  __builtin_amdgcn_global_load_lds(
      (__attribute__((address_space(1))) void*)(g),
      (__attribute__((address_space(3))) void*)(l), 16, 0, 0);
}

// XOR-swizzled element offset for logical (row, 16B-seg) in a [rows][32] bf16
// tile (64B rows). Involution: applying to (row, seg) twice restores.
__device__ __forceinline__ int swz_off(int row, int seg) {
  return row * 32 + ((seg ^ ((row >> 1) & 3)) << 3);
}

// Stage a 128x32 bf16 tile from row-major src (leading dim ld) into lds[128*32]
// via global_load_lds, with pre-swizzled global source (inverse of swz_off).
__device__ __forceinline__ void stage128x32_async(const bf16* src, int ld,
                                                  bf16* lds, int tid) {
  int r = tid >> 2;                                      // 0..63
  int seg_log = (((tid & 3) ^ ((tid >> 3) & 3))) * 8;    // inverse-swizzled seg
  gload_lds16(src + (size_t)r * ld + seg_log, lds + tid * 8);
  gload_lds16(src + (size_t)(r + 64) * ld + seg_log, lds + tid * 8 + 2048);
}

__device__ __forceinline__ void mfma_tile(const bf16* la, const bf16* lb,
                                          int wm, int wn, int fm, int fq,
                                          floatx4 (&acc)[4][4]) {
  bf16x8 af[4], bfr[4];
#pragma unroll
  for (int i = 0; i < 4; i++)
    af[i] = *(const bf16x8*)(la + swz_off(wm + i * 16 + fm, fq));
#pragma unroll
  for (int j = 0; j < 4; j++)
    bfr[j] = *(const bf16x8*)(lb + swz_off(wn + j * 16 + fm, fq));
#pragma unroll
  for (int i = 0; i < 4; i++)
#pragma unroll
    for (int j = 0; j < 4; j++)
      acc[i][j] = MFMA_BF16(af[i], bfr[j], acc[i][j]);
}

__device__ __forceinline__ float sigmoidf_(float x) { return 1.0f / (1.0f + __expf(-x)); }
__device__ __forceinline__ unsigned short bfbits(float x) {
  bf16 h = __float2bfloat16(x);
  return *reinterpret_cast<unsigned short*>(&h);
}

// ---------------- dtype detector: 1 = bf16 stream, 0 = fp32 stream ----------
__global__ void k_detect(const unsigned short* __restrict__ in, int* __restrict__ flag) {
  if (threadIdx.x == 0 && blockIdx.x == 0) {
    int cnt = 0;
    for (int i = 0; i < 512; i++) {
      int e = (in[i] >> 7) & 0xFF;
      if (e >= 114 && e <= 140) cnt++;
      }
    *flag = (cnt >= 450) ? 1 : 0;
  }
}

// ---------------- generic convert (bf16 copy or fp32->bf16) -----------------
__global__ __launch_bounds__(256) void k_cvt(const void* __restrict__ src,
                                             bf16* __restrict__ dst,
                                             const int* __restrict__ flag, int n) {
  int i = blockIdx.x * 256 + threadIdx.x;
  if (i >= n) return;
  if (*flag)
    dst[i] = ((const bf16*)src)[i];
  else
    dst[i] = __float2bfloat16(((const float*)src)[i]);
}

// ---------------- Gram: G[b][n][m] = sum_c X[b][n][c] * Y[b][m][c] ----------
// grid (8, 8, ZB), block 256. X,Y: [ZB][1024][512] bf16. G: [ZB][1024][1024] f32.
// Block id == x (mod 8): G row-block x of all batches is produced on XCD x.
__global__ __launch_bounds__(256, 2) void k_gram(const bf16* __restrict__ X,
                                                 const bf16* __restrict__ Y,
                                                 float* __restrict__ G) {
  int b = blockIdx.z;
  const bf16* Ab = X + (size_t)b * 524288 + (size_t)blockIdx.x * 128 * 512;
  const bf16* Bb = Y + (size_t)b * 524288 + (size_t)blockIdx.y * 128 * 512;
  __shared__ __align__(16) bf16 la[4096], lb[4096];
  int tid = threadIdx.x, wave = tid >> 6, lane = tid & 63;
  int wm = (wave & 1) * 64, wn = (wave >> 1) * 64, fm = lane & 15, fq = lane >> 4;
  floatx4 acc[4][4] = {};
  for (int kc = 0; kc < 512; kc += 32) {
    __syncthreads();
    stage128x32_async(Ab + kc, 512, la, tid);
    stage128x32_async(Bb + kc, 512, lb, tid);
    __syncthreads();
    mfma_tile(la, lb, wm, wn, fm, fq, acc);
  }
  size_t gb = (size_t)b * 1048576;
  int row0 = blockIdx.x * 128 + wm + fq * 4;
  int col0 = blockIdx.y * 128 + wn + fm;
#pragma unroll
  for (int i = 0; i < 4; i++)
#pragma unroll
    for (int j = 0; j < 4; j++)
#pragma unroll
      for (int r = 0; r < 4; r++)
        G[gb + (size_t)(row0 + i * 16 + r) * 1024 + col0 + j * 16] = acc[i][j][r];
}

// ---------------- fused softmax + att ---------------------------------------
// out[b][n][c] = sum_m softmax_m(G[b][n][:])[m] * Ycn[b][c][m]
// grid (32, 8), 256 threads (4 waves). Block owns 32 n-rows x all 512 c.
// Stats in-block (rows partition blocks: exp count 1x). la staged from G f32
// with exp applied (f32 math == old softmax; bf16 rounding identical).
// XCD-homing: bid&7 == row-block == gram producer's XCD.
__global__ __launch_bounds__(256, 2) void k_att3(const float* __restrict__ G,
                                                 const bf16* __restrict__ Ycn,
                                                 bf16* __restrict__ out) {
  int bid = blockIdx.x;                       // XCD home = bid & 7
  int x2 = ((bid & 7) << 2) | (bid >> 3);     // bijective: row-tile, rows x2*32..+32
  int z = blockIdx.y;
  const float* Gb = G + (size_t)z * 1048576 + (size_t)x2 * 32 * 1024;
  const bf16* Yb = Ycn + (size_t)z * 524288;
  __shared__ __align__(16) bf16 la[1024];      // [32][32] swizzled P tile
  __shared__ __align__(16) bf16 lb[16384];     // [512][32] swizzled (4x128 sub-tiles)
  __shared__ float sstat[64];                  // m[0..32), inv[32..64)
  int tid = threadIdx.x, wave = tid >> 6, lane = tid & 63;
  int fm = lane & 15, fq = lane >> 4;

  // ---- stats prologue: wave w handles rows [w*8, w*8+8) ----
  for (int rr = 0; rr < 8; rr++) {
    int row = wave * 8 + rr;
    const float4* g4 = (const float4*)(Gb + (size_t)row * 1024);
    float4 v0 = g4[lane], v1 = g4[lane + 64];
    float4 v2 = g4[lane + 128], v3 = g4[lane + 192];
    float m = fmaxf(fmaxf(fmaxf(fmaxf(v0.x, v0.y), fmaxf(v0.z, v0.w)),
                          fmaxf(fmaxf(v1.x, v1.y), fmaxf(v1.z, v1.w))),
                    fmaxf(fmaxf(fmaxf(v2.x, v2.y), fmaxf(v2.z, v2.w)),
                          fmaxf(fmaxf(v3.x, v3.y), fmaxf(v3.z, v3.w))));
    for (int off = 32; off > 0; off >>= 1) m = fmaxf(m, __shfl_xor(m, off));
    float s = __expf(v0.x - m) + __expf(v0.y - m) + __expf(v0.z - m) + __expf(v0.w - m)
            + __expf(v1.x - m) + __expf(v1.y - m) + __expf(v1.z - m) + __expf(v1.w - m)
            + __expf(v2.x - m) + __expf(v2.y - m) + __expf(v2.z - m) + __expf(v2.w - m)
            + __expf(v3.x - m) + __expf(v3.y - m) + __expf(v3.z - m) + __expf(v3.w - m);
    for (int off = 32; off > 0; off >>= 1) s += __shfl_xor(s, off);
    if (lane == 0) { sstat[row] = m; sstat[32 + row] = 1.0f / s; }
  }
  __syncthreads();

  bool doLa = (tid < 128);
  int lrow = tid >> 2, lsg = tid & 3;          // la slot (valid when doLa)
  float sm = 0.0f, sinv = 0.0f;
  if (doLa) { sm = sstat[lrow]; sinv = sstat[32 + lrow]; }

  floatx4 acc[2][8] = {};
  for (int kc = 0; kc < 1024; kc += 32) {
    __syncthreads();                           // previous iter's reads done
    // lb: Ycn rows [0,512) x cols [kc,kc+32), four 128-row sub-stages (DMA)
    stage128x32_async(Yb + kc, 1024, lb, tid);
    stage128x32_async(Yb + 131072 + kc, 1024, lb + 4096, tid);
    stage128x32_async(Yb + 262144 + kc, 1024, lb + 8192, tid);
    stage128x32_async(Yb + 393216 + kc, 1024, lb + 12288, tid);
    // la: P = exp(G - m) * inv, reg-staged (swizzled write)
    if (doLa) {
      const float* gs = Gb + (size_t)lrow * 1024 + kc + lsg * 8;
      float4 a = *(const float4*)gs;
      float4 b4 = *(const float4*)(gs + 4);
      bf16x8 p;
      p[0] = (short)bfbits(__expf(a.x - sm) * sinv);
      p[1] = (short)bfbits(__expf(a.y - sm) * sinv);
      p[2] = (short)bfbits(__expf(a.z - sm) * sinv);
      p[3] = (short)bfbits(__expf(a.w - sm) * sinv);
      p[4] = (short)bfbits(__expf(b4.x - sm) * sinv);
      p[5] = (short)bfbits(__expf(b4.y - sm) * sinv);
      p[6] = (short)bfbits(__expf(b4.z - sm) * sinv);
      p[7] = (short)bfbits(__expf(b4.w - sm) * sinv);
      *(bf16x8*)(la + swz_off(lrow, lsg)) = p;
    }
    __syncthreads();
    bf16x8 af[2], bfr[8];
    af[0] = *(const bf16x8*)(la + swz_off(fm, fq));
    af[1] = *(const bf16x8*)(la + swz_off(16 + fm, fq));
#pragma unroll
    for (int j = 0; j < 8; j++)
      bfr[j] = *(const bf16x8*)(lb + swz_off(wave * 128 + j * 16 + fm, fq));
#pragma unroll
    for (int i = 0; i < 2; i++)
#pragma unroll
      for (int j = 0; j < 8; j++)
        acc[i][j] = MFMA_BF16(af[i], bfr[j], acc[i][j]);
  }
  size_t ob = (size_t)z * 524288;
  int row0 = x2 * 32 + fq * 4;
  int c0 = wave * 128 + fm;
#pragma unroll
  for (int i = 0; i < 2; i++)
#pragma unroll
    for (int j = 0; j < 8; j++)
#pragma unroll
      for (int r = 0; r < 4; r++)
        out[ob + (size_t)(row0 + i * 16 + r) * 512 + c0 + j * 16] =
            __float2bfloat16(acc[i][j][r]);
}

// ---------------- GRU r+u merged: grid (384, 8) -----------------------------
// y<4: rh = sigmoid(A.Wr + br) * h ; y>=4: u = sigmoid(A.Wu + bu)
__global__ __launch_bounds__(256, 2) void k_gru01(const bf16* __restrict__ xb,
                                                  const bf16* __restrict__ hb,
                                                  const bf16* __restrict__ wR,
                                                  const bf16* __restrict__ bR,
                                                  const bf16* __restrict__ wU,
                                                  const bf16* __restrict__ bU,
                                                  bf16* __restrict__ rh_out,
                                                  bf16* __restrict__ u_out) {
  size_t row0 = (size_t)blockIdx.x * 128;
  int y = blockIdx.y;
  bool isR = (y < 4);
  int yy = isR ? y : (y - 4);
  const bf16* W = (isR ? wR : wU) + (size_t)yy * 128 * 1024;
  const bf16* bias = isR ? bR : bU;
  bf16* outp = isR ? rh_out : u_out;
  __shared__ __align__(16) bf16 la[4096], lb[4096];
  int tid = threadIdx.x, wave = tid >> 6, lane = tid & 63;
  int wm = (wave & 1) * 64, wn = (wave >> 1) * 64, fm = lane & 15, fq = lane >> 4;
  floatx4 acc[4][4] = {};
  for (int kc = 0; kc < 1024; kc += 32) {
    __syncthreads();
    const bf16* s_ = (kc < 512) ? (xb + row0 * 512 + kc) : (hb + row0 * 512 + (kc - 512));
    stage128x32_async(s_, 512, la, tid);
    stage128x32_async(W + kc, 1024, lb, tid);
    __syncthreads();
    mfma_tile(la, lb, wm, wn, fm, fq, acc);
  }
  int r0 = wm + fq * 4;
  int c0 = yy * 128 + wn + fm;
#pragma unroll
  for (int i = 0; i < 4; i++)
#pragma unroll
    for (int j = 0; j < 4; j++) {
      int co = c0 + j * 16;
      float bj = __bfloat162float(bias[co]);
#pragma unroll
      for (int r = 0; r < 4; r++) {
        size_t idx = (row0 + r0 + i * 16 + r) * 512 + co;
        float v = sigmoidf_(acc[i][j][r] + bj);
        if (isR)
          outp[idx] = __float2bfloat16(v * __bfloat162float(hb[idx]));
        else
          outp[idx] = __float2bfloat16(v);
      }
    }
}

// ---------------- GRU candidate + state update ------------------------------
__global__ __launch_bounds__(256, 2) void k_gru2(const bf16* __restrict__ xb,
                                                 const bf16* __restrict__ rhb,
                                                 const bf16* __restrict__ W,
                                                 const bf16* __restrict__ bias,
                                                 bf16* __restrict__ h_state,
                                                 const bf16* __restrict__ u_buf) {
  size_t row0 = (size_t)blockIdx.x * 128;
  const bf16* Wb = W + (size_t)blockIdx.y * 128 * 1024;
  __shared__ __align__(16) bf16 la[4096], lb[4096];
  int tid = threadIdx.x, wave = tid >> 6, lane = tid & 63;
  int wm = (wave & 1) * 64, wn = (wave >> 1) * 64, fm = lane & 15, fq = lane >> 4;
  floatx4 acc[4][4] = {};
  for (int kc = 0; kc < 1024; kc += 32) {
    __syncthreads();
    const bf16* s_ = (kc < 512) ? (xb + row0 * 512 + kc) : (rhb + row0 * 512 + (kc - 512));
    stage128x32_async(s_, 512, la, tid);
    stage128x32_async(Wb + kc, 1024, lb, tid);
    __syncthreads();
    mfma_tile(la, lb, wm, wn, fm, fq, acc);
  }
  int r0 = wm + fq * 4;
  int c0 = blockIdx.y * 128 + wn + fm;
#pragma unroll
  for (int i = 0; i < 4; i++)
#pragma unroll
    for (int j = 0; j < 4; j++) {
      int co = c0 + j * 16;
      float bj = __bfloat162float(bias[co]);
#pragma unroll
      for (int r = 0; r < 4; r++) {
        size_t idx = (row0 + r0 + i * 16 + r) * 512 + co;
        float cv = tanhf(acc[i][j][r] + bj);
        float uu = __bfloat162float(u_buf[idx]);
        float h = __bfloat162float(h_state[idx]);
        h_state[idx] = __float2bfloat16(h * (1.0f - uu) + cv * uu);
      }
    }
}

// ---------------- 3x3 conv (pad 1), implicit GEMM, counted-vmcnt pipeline ---
// grid (8, 4, Z). Weights DMA'd 2 taps ahead into lw[3]; raw s_barrier +
// counted vmcnt (never 0 in loop). lin staged T14-style: 4 unconditional
// clamped b128 loads at tap0 -> regs -> ds_write at end-of-cc.
__global__ __launch_bounds__(256, 3) void k_conv3(const bf16* __restrict__ src0,
                                                  const bf16* __restrict__ src1,
                                                  const bf16* __restrict__ wT,
                                                  const bf16* __restrict__ bias,
                                                  bf16* __restrict__ out) {
  int z = blockIdx.z;
  int y0 = blockIdx.x * 4;
  int co0 = blockIdx.y * 128;
  __shared__ __align__(16) bf16 lin[6528];     // [6][34][32] halo tile (swizzled)
  __shared__ __align__(16) bf16 lw[3][4096];   // 3-deep weight buffers [128][32]
  int tid = threadIdx.x, wave = tid >> 6, lane = tid & 63;
  int wm = (wave & 1) * 64, wn = (wave >> 1) * 64, fm = lane & 15, fq = lane >> 4;
  floatx4 acc[4][4] = {};
  const bf16* s0 = src0 + (size_t)z * 524288;
  const bf16* s1 = src1 + (size_t)z * 524288;
  int r_ = tid >> 2;
  int segl_ = (((tid & 3) ^ ((tid >> 3) & 3))) * 8;   // inverse-swizzled source seg

  // per-thread lin slot geometry (4 slots, clamped for uniform vmcnt counts)
  int sl_p[4], sl_sg[4], sl_off[4];
  bool sl_v[4];
#pragma unroll
  for (int k = 0; k < 4; k++) {
    int slot = k * 256 + tid;
    int sl = slot < 816 ? slot : 815;
    int p = sl >> 2, sg = sl & 3;
    int yy = p / 34, xx = p - yy * 34;
    int y = y0 + yy - 1, x = xx - 1;
    sl_v[k] = (slot < 816) && (y >= 0) && (y <= 31) && (x >= 0) && (x <= 31);
    int yc = min(max(y, 0), 31), xc = min(max(x, 0), 31);
    sl_p[k] = p; sl_sg[k] = sg;
    sl_off[k] = (yc * 32 + xc) * 512 + sg * 8;
  }
  bf16x8 lreg[4];
  const bf16x8 zero8 = {0, 0, 0, 0, 0, 0, 0, 0};

  auto lin_load = [&](int cc) {   // raw loads only; select deferred to write
    const bf16* sb = (cc < 16) ? (s0 + cc * 32) : (s1 + (cc - 16) * 32);
#pragma unroll
    for (int k = 0; k < 4; k++)
      lreg[k] = *(const bf16x8*)(sb + sl_off[k]);
  };
  auto lin_write = [&]() {
#pragma unroll
    for (int k = 0; k < 4; k++)
      if (k * 256 + tid < 816)
        *(bf16x8*)(lin + swz_off(sl_p[k], sl_sg[k])) = sl_v[k] ? lreg[k] : zero8;
  };
  auto issueW = [&](int cc, int t) {   // 2 DMA loads -> lw[t%3]
    const bf16* wsrc = wT + ((size_t)t * 512 + co0) * 1024 + cc * 32;
    bf16* dst = lw[t % 3];
    gload_lds16(wsrc + (size_t)r_ * 1024 + segl_, dst + tid * 8);
    gload_lds16(wsrc + (size_t)(r_ + 64) * 1024 + segl_, dst + tid * 8 + 2048);
  };

  // prologue: lin(0) staged synchronously; W(0,0), W(0,1) in flight
  lin_load(0);
  lin_write();              // compiler inserts the vmcnt wait for lreg here
  issueW(0, 0);
  issueW(0, 1);
  asm volatile("s_waitcnt lgkmcnt(0)" ::: "memory");   // lin writes committed

  for (int cc = 0; cc < 32; cc++) {
#pragma unroll
    for (int t = 0; t < 9; t++) {
      if (t == 1 || t == 2)
        asm volatile("s_waitcnt vmcnt(6)" ::: "memory");
      else
        asm volatile("s_waitcnt vmcnt(2)" ::: "memory");
      if (t == 0)
        asm volatile("s_waitcnt lgkmcnt(0)" ::: "memory");  // lin(cc) published
      __builtin_amdgcn_s_barrier();
      __builtin_amdgcn_sched_barrier(0);   // pin ds_reads/DMA below barrier
      int dy = t / 3 - 1, dx = t % 3 - 1;
      bf16x8 af[4], bfr[4];
#pragma unroll
      for (int i = 0; i < 4; i++) {
        int j = wm + i * 16 + fm;
        int jy = j >> 5, jx = j & 31;
        int p = (jy + dy + 1) * 34 + (jx + dx + 1);
        af[i] = *(const bf16x8*)(lin + swz_off(p, fq));
      }
#pragma unroll
      for (int jj = 0; jj < 4; jj++)
        bfr[jj] = *(const bf16x8*)(lw[t % 3] + swz_off(wn + jj * 16 + fm, fq));
      // prefetch weights for tap t+2 (dummy cc=0 reload at the very end)
      {
        int tt = t + 2;
        int ccn = cc + (tt >= 9 ? 1 : 0);
        int tn = tt >= 9 ? tt - 9 : tt;
        if (ccn >= 32) ccn = 0;            // harmless dummy, keeps counts uniform
        issueW(ccn, tn);
      }
      if (t == 0) {
        __builtin_amdgcn_sched_barrier(0); // pin L after W(cc,2): count contract
        lin_load(cc < 31 ? cc + 1 : cc);   // raw loads only (dummy at cc=31)
        __builtin_amdgcn_sched_barrier(0);
      }
      asm volatile("s_waitcnt lgkmcnt(0)" ::: "memory");
      __builtin_amdgcn_sched_barrier(0);   // rule 18: MFMA must not hoist
      __builtin_amdgcn_s_setprio(1);
#pragma unroll
      for (int i = 0; i < 4; i++)
#pragma unroll
        for (int jj = 0; jj < 4; jj++)
          acc[i][jj] = MFMA_BF16(af[i], bfr[jj], acc[i][jj]);
      __builtin_amdgcn_s_setprio(0);
      __builtin_amdgcn_sched_barrier(0);   // keep cluster placed
    }
    // all waves done reading lin (tap8 reads retired pre-MFMA) -> republish
    __builtin_amdgcn_s_barrier();
    __builtin_amdgcn_sched_barrier(0);
    lin_write();   // compiler inserts vmcnt wait for lreg; lgkm(0) at next tap0
  }
  asm volatile("s_waitcnt vmcnt(0)" ::: "memory");  // drain dummy DMAs pre-dealloc

  size_t ob = (size_t)z * 524288;
  int row0 = blockIdx.x * 128 + wm + fq * 4;
  int c0 = co0 + wn + fm;
#pragma unroll
  for (int i = 0; i < 4; i++)
#pragma unroll
    for (int jj = 0; jj < 4; jj++) {
      int co = c0 + jj * 16;
      float bj = __bfloat162float(bias[co]);
#pragma unroll
      for (int r = 0; r < 4; r++)
        out[ob + (size_t)(row0 + i * 16 + r) * 512 + co] =
            __float2bfloat16(acc[i][jj][r] + bj);
    }
}

// ---------------- bf16 transpose [R][C] -> [C][R] per z ---------------------
__global__ __launch_bounds__(256) void k_transpose(const bf16* __restrict__ src,
                                                   bf16* __restrict__ dst,
                                                   int R, int C) {
  __shared__ bf16 t[32][33];
  size_t zoff = (size_t)blockIdx.z * R * C;
  int c0 = blockIdx.x * 32, r0 = blockIdx.y * 32;
  int x = threadIdx.x & 31, y4 = (threadIdx.x >> 5) * 4;
#pragma unroll
  for (int i = 0; i < 4; i++)
    t[y4 + i][x] = src[zoff + (size_t)(r0 + y4 + i) * C + c0 + x];
  __syncthreads();
#pragma unroll
  for (int i = 0; i < 4; i++)
    dst[zoff + (size_t)(c0 + y4 + i) * R + r0 + x] = t[x][y4 + i];
}

// ---------------- final store: [1024][512] NHWC -> d_out [512][1024] --------
__global__ __launch_bounds__(256) void k_store(const bf16* __restrict__ src,
                                               void* __restrict__ dst,
                                               const int* __restrict__ flag) {
  __shared__ bf16 t[32][33];
  size_t zoff = (size_t)blockIdx.z * 524288;
  int c0 = blockIdx.x * 32, r0 = blockIdx.y * 32;
  int x = threadIdx.x & 31, y4 = (threadIdx.x >> 5) * 4;
#pragma unroll
  for (int i = 0; i < 4; i++)
    t[y4 + i][x] = src[zoff + (size_t)(r0 + y4 + i) * 512 + c0 + x];
  __syncthreads();
  bool isbf = (*flag != 0);
#pragma unroll
  for (int i = 0; i < 4; i++) {
    bf16 v = t[x][y4 + i];
    size_t o = zoff + (size_t)(c0 + y4 + i) * 1024 + r0 + x;
    if (isbf) ((bf16*)dst)[o] = v;
    else ((float*)dst)[o] = __bfloat162float(v);
  }
}

// ---------------- init: NCHW inputs -> state_h (NHWC) + state_c (NCHW) ------
__global__ __launch_bounds__(256) void k_init(const void* __restrict__ in1,
                                              const void* __restrict__ in2,
                                              const void* __restrict__ in3,
                                              bf16* __restrict__ state_h,
                                              bf16* __restrict__ state_c,
                                              const int* __restrict__ flag) {
  int z = blockIdx.z, s = z >> 4, b = z & 15;
  const void* srcv = (s == 0 ? in1 : (s == 1 ? in2 : in3));
  bool isbf = (*flag != 0);
  size_t base = (size_t)b * 524288;
  size_t dz = (size_t)z * 524288;
  int n0 = blockIdx.x * 32, c0 = blockIdx.y * 32;
  __shared__ bf16 t[32][33];
  int x = threadIdx.x & 31, y4 = (threadIdx.x >> 5) * 4;
#pragma unroll
  for (int i = 0; i < 4; i++) {
    size_t off = base + (size_t)(c0 + y4 + i) * 1024 + n0 + x;
    bf16 v = isbf ? ((const bf16*)srcv)[off]
                  : __float2bfloat16(((const float*)srcv)[off]);
    t[y4 + i][x] = v;
    state_c[dz + (size_t)(c0 + y4 + i) * 1024 + n0 + x] = v;
  }
  __syncthreads();
#pragma unroll
  for (int i = 0; i < 4; i++)
    state_h[dz + (size_t)(n0 + y4 + i) * 512 + c0 + x] = t[x][y4 + i];
}

// ---------------- inputs NCHW -> NHWC (for final conv) ----------------------
__global__ __launch_bounds__(256) void k_in_nhwc(const void* __restrict__ in1,
                                                 const void* __restrict__ in2,
                                                 const void* __restrict__ in3,
                                                 bf16* __restrict__ dst,
                                                 const int* __restrict__ flag) {
  int z = blockIdx.z, s = z >> 4, b = z & 15;
  const void* srcv = (s == 0 ? in1 : (s == 1 ? in2 : in3));
  bool isbf = (*flag != 0);
  size_t base = (size_t)b * 524288;
  size_t dz = (size_t)z * 524288;
  int n0 = blockIdx.x * 32, c0 = blockIdx.y * 32;
  __shared__ bf16 t[32][33];
  int x = threadIdx.x & 31, y4 = (threadIdx.x >> 5) * 4;
#pragma unroll
  for (int i = 0; i < 4; i++) {
    size_t off = base + (size_t)(c0 + y4 + i) * 1024 + n0 + x;
    t[y4 + i][x] = isbf ? ((const bf16*)srcv)[off]
                        : __float2bfloat16(((const float*)srcv)[off]);
  }
  __syncthreads();
#pragma unroll
  for (int i = 0; i < 4; i++)
    dst[dz + (size_t)(n0 + y4 + i) * 512 + c0 + x] = t[x][y4 + i];
}

// ---------------- weight transform: [co][ci][3][3] -> [tap][co][ci] ---------
__global__ __launch_bounds__(256) void k_wtrans(const void* __restrict__ w,
                                                bf16* __restrict__ wT,
                                                const int* __restrict__ flag) {
  int idx = blockIdx.x * 256 + threadIdx.x;
  bool isbf = (*flag != 0);
#pragma unroll
  for (int t = 0; t < 9; t++) {
    bf16 v = isbf ? ((const bf16*)w)[(size_t)idx * 9 + t]
                  : __float2bfloat16(((const float*)w)[(size_t)idx * 9 + t]);
    wT[(size_t)t * 524288 + idx] = v;
  }
}

extern "C" void kernel_launch(void* const* d_in, const int* in_sizes, int n_in,
                              void* d_out, int out_size, void* d_ws, size_t ws_size,
                              hipStream_t stream) {
  (void)in_sizes; (void)n_in; (void)out_size; (void)ws_size;
  const void* in1 = d_in[0];
  const void* in2 = d_in[1];
  const void* in3 = d_in[2];

  char* ws = (char*)d_ws;
  bf16* state_h = (bf16*)(ws + 0);
  bf16* state_c = (bf16*)(ws + 50331648);
  bf16* AttA    = (bf16*)(ws + 100663296);
  bf16* RHbuf   = (bf16*)(ws + 100663296);
  bf16* in_nhwc = (bf16*)(ws + 100663296);
  bf16* AttB    = (bf16*)(ws + 150994944);
  bf16* Ubuf    = (bf16*)(ws + 150994944);
  bf16* OutTmp  = (bf16*)(ws + 150994944);
  float* Gbuf   = (float*)(ws + 201326592);
  bf16* wT_out  = (bf16*)(ws + 201326592);   // after rounds only
  bf16* wT_fus  = (bf16*)(ws + 234881024);
  bf16* wR      = (bf16*)(ws + 244318208);
  bf16* wU      = (bf16*)(ws + 245366784);
  bf16* wC      = (bf16*)(ws + 246415360);
  bf16* bF      = (bf16*)(ws + 247463936);
  bf16* bO      = (bf16*)(ws + 247465984);
  bf16* bR      = (bf16*)(ws + 247468032);
  bf16* bU      = (bf16*)(ws + 247470080);
  bf16* bC      = (bf16*)(ws + 247472128);
  int*  flag    = (int*)(ws + 247474176);
  bf16* Abuf    = (bf16*)d_out;

  const size_t SLICE = 16 * 1024 * 512;   // elements per state slice
  const size_t CHUNK = 8 * 1024 * 512;    // elements per batch-chunk

  k_detect<<<1, 64, 0, stream>>>((const unsigned short*)d_in[0], flag);
  k_cvt<<<2048, 256, 0, stream>>>(d_in[7], wR, flag, 524288);
  k_cvt<<<2048, 256, 0, stream>>>(d_in[9], wU, flag, 524288);
  k_cvt<<<2048, 256, 0, stream>>>(d_in[11], wC, flag, 524288);
  k_cvt<<<2, 256, 0, stream>>>(d_in[4], bF, flag, 512);
  k_cvt<<<2, 256, 0, stream>>>(d_in[6], bO, flag, 512);
  k_cvt<<<2, 256, 0, stream>>>(d_in[8], bR, flag, 512);
  k_cvt<<<2, 256, 0, stream>>>(d_in[10], bU, flag, 512);
  k_cvt<<<2, 256, 0, stream>>>(d_in[12], bC, flag, 512);
  k_wtrans<<<2048, 256, 0, stream>>>(d_in[3], wT_fus, flag);
  k_init<<<dim3(32, 16, 48), 256, 0, stream>>>(in1, in2, in3, state_h, state_c, flag);

  const int sx[6] = {0, 0, 1, 1, 2, 2};
  const int sy[6] = {1, 2, 0, 2, 0, 1};
  for (int round = 0; round < 5; ++round) {
    for (int p = 0; p < 3; ++p) {
      for (int h = 0; h < 2; ++h) {
        int i = p * 2 + h;
        bf16* attdst = (h == 0 ? AttA : AttB) + p * SLICE;
        for (int cb = 0; cb < 2; ++cb) {
          size_t co = (size_t)cb * CHUNK;
          k_gram<<<dim3(8, 8, 8), 256, 0, stream>>>(
              state_h + sx[i] * SLICE + co, state_h + sy[i] * SLICE + co, Gbuf);
          k_att3<<<dim3(32, 8), 256, 0, stream>>>(
              Gbuf, state_c + sy[i] * SLICE + co, attdst + co);
        }
      }
    }
    k_conv3<<<dim3(8, 4, 48), 256, 0, stream>>>(AttA, AttB, wT_fus, bF, Abuf);
    k_gru01<<<dim3(384, 8), 256, 0, stream>>>(Abuf, state_h, wR, bR, wU, bU,
                                              RHbuf, Ubuf);
    k_gru2<<<dim3(384, 4), 256, 0, stream>>>(Abuf, RHbuf, wC, bC, state_h, Ubuf);
    k_transpose<<<dim3(16, 32, 48), 256, 0, stream>>>(state_h, state_c, 1024, 512);
  }
  k_wtrans<<<2048, 256, 0, stream>>>(d_in[5], wT_out, flag);
  k_in_nhwc<<<dim3(32, 16, 48), 256, 0, stream>>>(in1, in2, in3, in_nhwc, flag);
  k_conv3<<<dim3(8, 4, 48), 256, 0, stream>>>(state_h, in_nhwc, wT_out, bO, OutTmp);
  k_store<<<dim3(16, 32, 48), 256, 0, stream>>>(OutTmp, d_out, flag);
}

// Round 10
// 6964.693 us; speedup vs baseline: 1.1476x; 1.1476x over previous
//
#include <hip/hip_runtime.h>
#include <hip/hip_bf16.h>

// R14 = R11 (verified 6989.6us) + counted-vmcnt pipeline on k_att ONLY.
//  R13 post-mortem: fused att3 regressed +1000us (4x Y staging traffic, 1
//  block/CU with tiny compute phase) -> reverted to R11's gram/softmax/att.
//  k_att is the only GEMM at 1 block/CU (grid 256): zero TLP, so the per-step
//  __syncthreads vmcnt(0) drain is fully exposed — same regime where R8's
//  conv3 pipeline won +17%. R9's bundled attempt regressed, but it bundled
//  known regressors (setprio-in-lockstep m190, sched_barrier-pinning m141)
//  and touched gram/gru (which have TLP). Here: R9's verified-correct sync
//  skeleton (la/lb[3], stage 2 ahead, uniform vmcnt(8), dummy tail stages,
//  trailing lgkm(0)+barrier) applied to k_att alone, WITHOUT setprio /
//  sched_barrier. Clean A/B vs measured R11.
// R11/R10: softmax XCD-homing (index-only, ~free). R8: conv3 counted-vmcnt
// pipeline (MfmaUtil 46->61%). R6: LDS XOR swizzle (conflicts 0).
// R5: global_load_lds staging. R4: persistent att outputs, conv3 z=48,
//  gru0+1 merged, S in-place over G rows.

using bf16 = __hip_bfloat16;
typedef __attribute__((ext_vector_type(8))) short bf16x8;
typedef __attribute__((ext_vector_type(4))) float floatx4;

#define MFMA_BF16(a, b, c) __builtin_amdgcn_mfma_f32_16x16x32_bf16((a), (b), (c), 0, 0, 0)

// Async 16B global->LDS DMA. LDS dest must be wave-uniform base + lane*16.
__device__ __forceinline__ void gload_lds16(const bf16* g, bf16* l) {
  __builtin_amdgcn_global_load_lds(
      (__attribute__((address_space(1))) void*)(g),
      (__attribute__((address_space(3))) void*)(l), 16, 0, 0);
}

// XOR-swizzled element offset for logical (row, 16B-seg) in a [rows][32] bf16
// tile (64B rows). Involution: applying to (row, seg) twice restores.
__device__ __forceinline__ int swz_off(int row, int seg) {
  return row * 32 + ((seg ^ ((row >> 1) & 3)) << 3);
}

// Stage a 128x32 bf16 tile from row-major src (leading dim ld) into lds[128*32]
// via global_load_lds, with pre-swizzled global source (inverse of swz_off).
__device__ __forceinline__ void stage128x32_async(const bf16* src, int ld,
                                                  bf16* lds, int tid) {
  int r = tid >> 2;                                      // 0..63
  int seg_log = (((tid & 3) ^ ((tid >> 3) & 3))) * 8;    // inverse-swizzled seg
  gload_lds16(src + (size_t)r * ld + seg_log, lds + tid * 8);
  gload_lds16(src + (size_t)(r + 64) * ld + seg_log, lds + tid * 8 + 2048);
}

__device__ __forceinline__ void mfma_tile(const bf16* la, const bf16* lb,
                                          int wm, int wn, int fm, int fq,
                                          floatx4 (&acc)[4][4]) {
  bf16x8 af[4], bfr[4];
#pragma unroll
  for (int i = 0; i < 4; i++)
    af[i] = *(const bf16x8*)(la + swz_off(wm + i * 16 + fm, fq));
#pragma unroll
  for (int j = 0; j < 4; j++)
    bfr[j] = *(const bf16x8*)(lb + swz_off(wn + j * 16 + fm, fq));
#pragma unroll
  for (int i = 0; i < 4; i++)
#pragma unroll
    for (int j = 0; j < 4; j++)
      acc[i][j] = MFMA_BF16(af[i], bfr[j], acc[i][j]);
}

__device__ __forceinline__ float sigmoidf_(float x) { return 1.0f / (1.0f + __expf(-x)); }
__device__ __forceinline__ unsigned short bfbits(float x) {
  bf16 h = __float2bfloat16(x);
  return *reinterpret_cast<unsigned short*>(&h);
}

// ---------------- dtype detector: 1 = bf16 stream, 0 = fp32 stream ----------
__global__ void k_detect(const unsigned short* __restrict__ in, int* __restrict__ flag) {
  if (threadIdx.x == 0 && blockIdx.x == 0) {
    int cnt = 0;
    for (int i = 0; i < 512; i++) {
      int e = (in[i] >> 7) & 0xFF;
      if (e >= 114 && e <= 140) cnt++;
      }
    *flag = (cnt >= 450) ? 1 : 0;
  }
}

// ---------------- generic convert (bf16 copy or fp32->bf16) -----------------
__global__ __launch_bounds__(256) void k_cvt(const void* __restrict__ src,
                                             bf16* __restrict__ dst,
                                             const int* __restrict__ flag, int n) {
  int i = blockIdx.x * 256 + threadIdx.x;
  if (i >= n) return;
  if (*flag)
    dst[i] = ((const bf16*)src)[i];
  else
    dst[i] = __float2bfloat16(((const float*)src)[i]);
}

// ---------------- Gram: G[b][n][m] = sum_c X[b][n][c] * Y[b][m][c] ----------
// grid (8, 8, ZB), block 256. X,Y: [ZB][1024][512] bf16. G: [ZB][1024][1024] f32.
// Block id == x (mod 8): G row-block x of all batches is produced on XCD x.
__global__ __launch_bounds__(256, 2) void k_gram(const bf16* __restrict__ X,
                                                 const bf16* __restrict__ Y,
                                                 float* __restrict__ G) {
  int b = blockIdx.z;
  const bf16* Ab = X + (size_t)b * 524288 + (size_t)blockIdx.x * 128 * 512;
  const bf16* Bb = Y + (size_t)b * 524288 + (size_t)blockIdx.y * 128 * 512;
  __shared__ __align__(16) bf16 la[4096], lb[4096];
  int tid = threadIdx.x, wave = tid >> 6, lane = tid & 63;
  int wm = (wave & 1) * 64, wn = (wave >> 1) * 64, fm = lane & 15, fq = lane >> 4;
  floatx4 acc[4][4] = {};
  for (int kc = 0; kc < 512; kc += 32) {
    __syncthreads();
    stage128x32_async(Ab + kc, 512, la, tid);
    stage128x32_async(Bb + kc, 512, lb, tid);
    __syncthreads();
    mfma_tile(la, lb, wm, wn, fm, fq, acc);
  }
  size_t gb = (size_t)b * 1048576;
  int row0 = blockIdx.x * 128 + wm + fq * 4;
  int col0 = blockIdx.y * 128 + wn + fm;
#pragma unroll
  for (int i = 0; i < 4; i++)
#pragma unroll
    for (int j = 0; j < 4; j++)
#pragma unroll
      for (int r = 0; r < 4; r++)
        G[gb + (size_t)(row0 + i * 16 + r) * 1024 + col0 + j * 16] = acc[i][j][r];
}

// ---------------- row softmax over m, S written IN PLACE over G row ---------
// XCD-homing remap: block id == c (mod 8) processes rows of row-block c
// (rows c*128..c*128+127 of every batch), which gram produced on XCD c.
// Bijective: id = c + 8*(z*128 + rsub), c<8, rsub<128, z<8 -> 8192 rows.
__global__ __launch_bounds__(256) void k_softmax(float* __restrict__ G) {
  int id = blockIdx.x;
  int c = id & 7;           // home XCD / row-block
  int j = id >> 3;          // 0..1023
  int rsub = j & 127;       // row within block
  int z = j >> 7;           // batch 0..7
  size_t row = (size_t)z * 1024 + (size_t)c * 128 + rsub;
  float* g = G + row * 1024;
  int tid = threadIdx.x, wave = tid >> 6, lane = tid & 63;
  float4 x = ((const float4*)g)[tid];
  float m = fmaxf(fmaxf(x.x, x.y), fmaxf(x.z, x.w));
  for (int off = 32; off > 0; off >>= 1) m = fmaxf(m, __shfl_xor(m, off));
  __shared__ float red[4], red2[4];
  if (lane == 0) red[wave] = m;
  __syncthreads();
  m = fmaxf(fmaxf(red[0], red[1]), fmaxf(red[2], red[3]));
  float e0 = __expf(x.x - m), e1 = __expf(x.y - m);
  float e2 = __expf(x.z - m), e3 = __expf(x.w - m);
  float s = e0 + e1 + e2 + e3;
  for (int off = 32; off > 0; off >>= 1) s += __shfl_xor(s, off);
  if (lane == 0) red2[wave] = s;
  __syncthreads();
  float inv = 1.0f / (red2[0] + red2[1] + red2[2] + red2[3]);
  ushort4 o;
  o.x = bfbits(e0 * inv); o.y = bfbits(e1 * inv);
  o.z = bfbits(e2 * inv); o.w = bfbits(e3 * inv);
  ((ushort4*)((bf16*)g))[tid] = o;
}

// ---------------- att[b][n][c] = sum_m S[b][n][m] * Ycn[b][c][m] ------------
// S lives in G's rows: ld = 2048 bf16, batch stride 1024*2048.
// Block id == x (mod 8): reads S row-block x from its home XCD's L2.
// Counted-vmcnt pipeline (R8 skeleton, no setprio/sched_barrier): la/lb[3],
// stage issued 2 K-steps ahead (4 loads/thread per step), uniform vmcnt(8)
// (12 outstanding - 8 newest => S_k retired), barrier; MFMA; lgkm(0)+barrier
// protects buf (k+2)%3 clobber (last read at iter k-1). Dummy tail stages
// (tile 0) keep the per-wave ledger uniform; final vmcnt(0) pre-dealloc.
__global__ __launch_bounds__(256, 2) void k_att(const bf16* __restrict__ S,
                                                const bf16* __restrict__ Ycn,
                                                bf16* __restrict__ out) {
  int b = blockIdx.z;
  const bf16* Ab = S + (size_t)b * 2097152 + (size_t)blockIdx.x * 128 * 2048;
  const bf16* Bb = Ycn + (size_t)b * 524288 + (size_t)blockIdx.y * 128 * 1024;
  __shared__ __align__(16) bf16 la[3][4096], lb[3][4096];
  int tid = threadIdx.x, wave = tid >> 6, lane = tid & 63;
  int wm = (wave & 1) * 64, wn = (wave >> 1) * 64, fm = lane & 15, fq = lane >> 4;
  floatx4 acc[4][4] = {};
  auto stage = [&](int ks) {
    int kk = (ks < 32 ? ks : 0) * 32;   // dummy tail re-stages tile 0
    int bu = ks % 3;
    stage128x32_async(Ab + kk, 2048, la[bu], tid);
    stage128x32_async(Bb + kk, 1024, lb[bu], tid);
  };
  stage(0);
  stage(1);
  for (int k = 0; k < 32; k++) {
    stage(k + 2);
    asm volatile("s_waitcnt vmcnt(8)" ::: "memory");   // S_k retired
    __builtin_amdgcn_s_barrier();
    mfma_tile(la[k % 3], lb[k % 3], wm, wn, fm, fq, acc);
    asm volatile("s_waitcnt lgkmcnt(0)" ::: "memory"); // my ds_reads done
    __builtin_amdgcn_s_barrier();                      // all waves done w/ buf
  }
  asm volatile("s_waitcnt vmcnt(0)" ::: "memory");     // drain dummies
  size_t ob = (size_t)b * 524288;
  int row0 = blockIdx.x * 128 + wm + fq * 4;
  int col0 = blockIdx.y * 128 + wn + fm;
#pragma unroll
  for (int i = 0; i < 4; i++)
#pragma unroll
    for (int j = 0; j < 4; j++)
#pragma unroll
      for (int r = 0; r < 4; r++)
        out[ob + (size_t)(row0 + i * 16 + r) * 512 + col0 + j * 16] =
            __float2bfloat16(acc[i][j][r]);
}

// ---------------- GRU r+u merged: grid (384, 8) -----------------------------
// y<4: rh = sigmoid(A.Wr + br) * h ; y>=4: u = sigmoid(A.Wu + bu)
__global__ __launch_bounds__(256, 2) void k_gru01(const bf16* __restrict__ xb,
                                                  const bf16* __restrict__ hb,
                                                  const bf16* __restrict__ wR,
                                                  const bf16* __restrict__ bR,
                                                  const bf16* __restrict__ wU,
                                                  const bf16* __restrict__ bU,
                                                  bf16* __restrict__ rh_out,
                                                  bf16* __restrict__ u_out) {
  size_t row0 = (size_t)blockIdx.x * 128;
  int y = blockIdx.y;
  bool isR = (y < 4);
  int yy = isR ? y : (y - 4);
  const bf16* W = (isR ? wR : wU) + (size_t)yy * 128 * 1024;
  const bf16* bias = isR ? bR : bU;
  bf16* outp = isR ? rh_out : u_out;
  __shared__ __align__(16) bf16 la[4096], lb[4096];
  int tid = threadIdx.x, wave = tid >> 6, lane = tid & 63;
  int wm = (wave & 1) * 64, wn = (wave >> 1) * 64, fm = lane & 15, fq = lane >> 4;
  floatx4 acc[4][4] = {};
  for (int kc = 0; kc < 1024; kc += 32) {
    __syncthreads();
    const bf16* s_ = (kc < 512) ? (xb + row0 * 512 + kc) : (hb + row0 * 512 + (kc - 512));
    stage128x32_async(s_, 512, la, tid);
    stage128x32_async(W + kc, 1024, lb, tid);
    __syncthreads();
    mfma_tile(la, lb, wm, wn, fm, fq, acc);
  }
  int r0 = wm + fq * 4;
  int c0 = yy * 128 + wn + fm;
#pragma unroll
  for (int i = 0; i < 4; i++)
#pragma unroll
    for (int j = 0; j < 4; j++) {
      int co = c0 + j * 16;
      float bj = __bfloat162float(bias[co]);
#pragma unroll
      for (int r = 0; r < 4; r++) {
        size_t idx = (row0 + r0 + i * 16 + r) * 512 + co;
        float v = sigmoidf_(acc[i][j][r] + bj);
        if (isR)
          outp[idx] = __float2bfloat16(v * __bfloat162float(hb[idx]));
        else
          outp[idx] = __float2bfloat16(v);
      }
    }
}

// ---------------- GRU candidate + state update ------------------------------
__global__ __launch_bounds__(256, 2) void k_gru2(const bf16* __restrict__ xb,
                                                 const bf16* __restrict__ rhb,
                                                 const bf16* __restrict__ W,
                                                 const bf16* __restrict__ bias,
                                                 bf16* __restrict__ h_state,
                                                 const bf16* __restrict__ u_buf) {
  size_t row0 = (size_t)blockIdx.x * 128;
  const bf16* Wb = W + (size_t)blockIdx.y * 128 * 1024;
  __shared__ __align__(16) bf16 la[4096], lb[4096];
  int tid = threadIdx.x, wave = tid >> 6, lane = tid & 63;
  int wm = (wave & 1) * 64, wn = (wave >> 1) * 64, fm = lane & 15, fq = lane >> 4;
  floatx4 acc[4][4] = {};
  for (int kc = 0; kc < 1024; kc += 32) {
    __syncthreads();
    const bf16* s_ = (kc < 512) ? (xb + row0 * 512 + kc) : (rhb + row0 * 512 + (kc - 512));
    stage128x32_async(s_, 512, la, tid);
    stage128x32_async(Wb + kc, 1024, lb, tid);
    __syncthreads();
    mfma_tile(la, lb, wm, wn, fm, fq, acc);
  }
  int r0 = wm + fq * 4;
  int c0 = blockIdx.y * 128 + wn + fm;
#pragma unroll
  for (int i = 0; i < 4; i++)
#pragma unroll
    for (int j = 0; j < 4; j++) {
      int co = c0 + j * 16;
      float bj = __bfloat162float(bias[co]);
#pragma unroll
      for (int r = 0; r < 4; r++) {
        size_t idx = (row0 + r0 + i * 16 + r) * 512 + co;
        float cv = tanhf(acc[i][j][r] + bj);
        float uu = __bfloat162float(u_buf[idx]);
        float h = __bfloat162float(h_state[idx]);
        h_state[idx] = __float2bfloat16(h * (1.0f - uu) + cv * uu);
      }
    }
}

// ---------------- 3x3 conv (pad 1), implicit GEMM, counted-vmcnt pipeline ---
// grid (8, 4, Z). Weights DMA'd 2 taps ahead into lw[3]; raw s_barrier +
// counted vmcnt (never 0 in loop). lin staged T14-style: 4 unconditional
// clamped b128 loads at tap0 -> regs -> ds_write at end-of-cc.
__global__ __launch_bounds__(256, 3) void k_conv3(const bf16* __restrict__ src0,
                                                  const bf16* __restrict__ src1,
                                                  const bf16* __restrict__ wT,
                                                  const bf16* __restrict__ bias,
                                                  bf16* __restrict__ out) {
  int z = blockIdx.z;
  int y0 = blockIdx.x * 4;
  int co0 = blockIdx.y * 128;
  __shared__ __align__(16) bf16 lin[6528];     // [6][34][32] halo tile (swizzled)
  __shared__ __align__(16) bf16 lw[3][4096];   // 3-deep weight buffers [128][32]
  int tid = threadIdx.x, wave = tid >> 6, lane = tid & 63;
  int wm = (wave & 1) * 64, wn = (wave >> 1) * 64, fm = lane & 15, fq = lane >> 4;
  floatx4 acc[4][4] = {};
  const bf16* s0 = src0 + (size_t)z * 524288;
  const bf16* s1 = src1 + (size_t)z * 524288;
  int r_ = tid >> 2;
  int segl_ = (((tid & 3) ^ ((tid >> 3) & 3))) * 8;   // inverse-swizzled source seg

  // per-thread lin slot geometry (4 slots, clamped for uniform vmcnt counts)
  int sl_p[4], sl_sg[4], sl_off[4];
  bool sl_v[4];
#pragma unroll
  for (int k = 0; k < 4; k++) {
    int slot = k * 256 + tid;
    int sl = slot < 816 ? slot : 815;
    int p = sl >> 2, sg = sl & 3;
    int yy = p / 34, xx = p - yy * 34;
    int y = y0 + yy - 1, x = xx - 1;
    sl_v[k] = (slot < 816) && (y >= 0) && (y <= 31) && (x >= 0) && (x <= 31);
    int yc = min(max(y, 0), 31), xc = min(max(x, 0), 31);
    sl_p[k] = p; sl_sg[k] = sg;
    sl_off[k] = (yc * 32 + xc) * 512 + sg * 8;
  }
  bf16x8 lreg[4];
  const bf16x8 zero8 = {0, 0, 0, 0, 0, 0, 0, 0};

  auto lin_load = [&](int cc) {   // raw loads only; select deferred to write
    const bf16* sb = (cc < 16) ? (s0 + cc * 32) : (s1 + (cc - 16) * 32);
#pragma unroll
    for (int k = 0; k < 4; k++)
      lreg[k] = *(const bf16x8*)(sb + sl_off[k]);
  };
  auto lin_write = [&]() {
#pragma unroll
    for (int k = 0; k < 4; k++)
      if (k * 256 + tid < 816)
        *(bf16x8*)(lin + swz_off(sl_p[k], sl_sg[k])) = sl_v[k] ? lreg[k] : zero8;
  };
  auto issueW = [&](int cc, int t) {   // 2 DMA loads -> lw[t%3]
    const bf16* wsrc = wT + ((size_t)t * 512 + co0) * 1024 + cc * 32;
    bf16* dst = lw[t % 3];
    gload_lds16(wsrc + (size_t)r_ * 1024 + segl_, dst + tid * 8);
    gload_lds16(wsrc + (size_t)(r_ + 64) * 1024 + segl_, dst + tid * 8 + 2048);
  };

  // prologue: lin(0) staged synchronously; W(0,0), W(0,1) in flight
  lin_load(0);
  lin_write();              // compiler inserts the vmcnt wait for lreg here
  issueW(0, 0);
  issueW(0, 1);
  asm volatile("s_waitcnt lgkmcnt(0)" ::: "memory");   // lin writes committed

  for (int cc = 0; cc < 32; cc++) {
#pragma unroll
    for (int t = 0; t < 9; t++) {
      if (t == 1 || t == 2)
        asm volatile("s_waitcnt vmcnt(6)" ::: "memory");
      else
        asm volatile("s_waitcnt vmcnt(2)" ::: "memory");
      if (t == 0)
        asm volatile("s_waitcnt lgkmcnt(0)" ::: "memory");  // lin(cc) published
      __builtin_amdgcn_s_barrier();
      __builtin_amdgcn_sched_barrier(0);   // pin ds_reads/DMA below barrier
      int dy = t / 3 - 1, dx = t % 3 - 1;
      bf16x8 af[4], bfr[4];
#pragma unroll
      for (int i = 0; i < 4; i++) {
        int j = wm + i * 16 + fm;
        int jy = j >> 5, jx = j & 31;
        int p = (jy + dy + 1) * 34 + (jx + dx + 1);
        af[i] = *(const bf16x8*)(lin + swz_off(p, fq));
      }
#pragma unroll
      for (int jj = 0; jj < 4; jj++)
        bfr[jj] = *(const bf16x8*)(lw[t % 3] + swz_off(wn + jj * 16 + fm, fq));
      // prefetch weights for tap t+2 (dummy cc=0 reload at the very end)
      {
        int tt = t + 2;
        int ccn = cc + (tt >= 9 ? 1 : 0);
        int tn = tt >= 9 ? tt - 9 : tt;
        if (ccn >= 32) ccn = 0;            // harmless dummy, keeps counts uniform
        issueW(ccn, tn);
      }
      if (t == 0) {
        __builtin_amdgcn_sched_barrier(0); // pin L after W(cc,2): count contract
        lin_load(cc < 31 ? cc + 1 : cc);   // raw loads only (dummy at cc=31)
        __builtin_amdgcn_sched_barrier(0);
      }
      asm volatile("s_waitcnt lgkmcnt(0)" ::: "memory");
      __builtin_amdgcn_sched_barrier(0);   // rule 18: MFMA must not hoist
      __builtin_amdgcn_s_setprio(1);
#pragma unroll
      for (int i = 0; i < 4; i++)
#pragma unroll
        for (int jj = 0; jj < 4; jj++)
          acc[i][jj] = MFMA_BF16(af[i], bfr[jj], acc[i][jj]);
      __builtin_amdgcn_s_setprio(0);
      __builtin_amdgcn_sched_barrier(0);   // keep cluster placed
    }
    // all waves done reading lin (tap8 reads retired pre-MFMA) -> republish
    __builtin_amdgcn_s_barrier();
    __builtin_amdgcn_sched_barrier(0);
    lin_write();   // compiler inserts vmcnt wait for lreg; lgkm(0) at next tap0
  }
  asm volatile("s_waitcnt vmcnt(0)" ::: "memory");  // drain dummy DMAs pre-dealloc

  size_t ob = (size_t)z * 524288;
  int row0 = blockIdx.x * 128 + wm + fq * 4;
  int c0 = co0 + wn + fm;
#pragma unroll
  for (int i = 0; i < 4; i++)
#pragma unroll
    for (int jj = 0; jj < 4; jj++) {
      int co = c0 + jj * 16;
      float bj = __bfloat162float(bias[co]);
#pragma unroll
      for (int r = 0; r < 4; r++)
        out[ob + (size_t)(row0 + i * 16 + r) * 512 + co] =
            __float2bfloat16(acc[i][jj][r] + bj);
    }
}

// ---------------- bf16 transpose [R][C] -> [C][R] per z ---------------------
__global__ __launch_bounds__(256) void k_transpose(const bf16* __restrict__ src,
                                                   bf16* __restrict__ dst,
                                                   int R, int C) {
  __shared__ bf16 t[32][33];
  size_t zoff = (size_t)blockIdx.z * R * C;
  int c0 = blockIdx.x * 32, r0 = blockIdx.y * 32;
  int x = threadIdx.x & 31, y4 = (threadIdx.x >> 5) * 4;
#pragma unroll
  for (int i = 0; i < 4; i++)
    t[y4 + i][x] = src[zoff + (size_t)(r0 + y4 + i) * C + c0 + x];
  __syncthreads();
#pragma unroll
  for (int i = 0; i < 4; i++)
    dst[zoff + (size_t)(c0 + y4 + i) * R + r0 + x] = t[x][y4 + i];
}

// ---------------- final store: [1024][512] NHWC -> d_out [512][1024] --------
__global__ __launch_bounds__(256) void k_store(const bf16* __restrict__ src,
                                               void* __restrict__ dst,
                                               const int* __restrict__ flag) {
  __shared__ bf16 t[32][33];
  size_t zoff = (size_t)blockIdx.z * 524288;
  int c0 = blockIdx.x * 32, r0 = blockIdx.y * 32;
  int x = threadIdx.x & 31, y4 = (threadIdx.x >> 5) * 4;
#pragma unroll
  for (int i = 0; i < 4; i++)
    t[y4 + i][x] = src[zoff + (size_t)(r0 + y4 + i) * 512 + c0 + x];
  __syncthreads();
  bool isbf = (*flag != 0);
#pragma unroll
  for (int i = 0; i < 4; i++) {
    bf16 v = t[x][y4 + i];
    size_t o = zoff + (size_t)(c0 + y4 + i) * 1024 + r0 + x;
    if (isbf) ((bf16*)dst)[o] = v;
    else ((float*)dst)[o] = __bfloat162float(v);
  }
}

// ---------------- init: NCHW inputs -> state_h (NHWC) + state_c (NCHW) ------
__global__ __launch_bounds__(256) void k_init(const void* __restrict__ in1,
                                              const void* __restrict__ in2,
                                              const void* __restrict__ in3,
                                              bf16* __restrict__ state_h,
                                              bf16* __restrict__ state_c,
                                              const int* __restrict__ flag) {
  int z = blockIdx.z, s = z >> 4, b = z & 15;
  const void* srcv = (s == 0 ? in1 : (s == 1 ? in2 : in3));
  bool isbf = (*flag != 0);
  size_t base = (size_t)b * 524288;
  size_t dz = (size_t)z * 524288;
  int n0 = blockIdx.x * 32, c0 = blockIdx.y * 32;
  __shared__ bf16 t[32][33];
  int x = threadIdx.x & 31, y4 = (threadIdx.x >> 5) * 4;
#pragma unroll
  for (int i = 0; i < 4; i++) {
    size_t off = base + (size_t)(c0 + y4 + i) * 1024 + n0 + x;
    bf16 v = isbf ? ((const bf16*)srcv)[off]
                  : __float2bfloat16(((const float*)srcv)[off]);
    t[y4 + i][x] = v;
    state_c[dz + (size_t)(c0 + y4 + i) * 1024 + n0 + x] = v;
  }
  __syncthreads();
#pragma unroll
  for (int i = 0; i < 4; i++)
    state_h[dz + (size_t)(n0 + y4 + i) * 512 + c0 + x] = t[x][y4 + i];
}

// ---------------- inputs NCHW -> NHWC (for final conv) ----------------------
__global__ __launch_bounds__(256) void k_in_nhwc(const void* __restrict__ in1,
                                                 const void* __restrict__ in2,
                                                 const void* __restrict__ in3,
                                                 bf16* __restrict__ dst,
                                                 const int* __restrict__ flag) {
  int z = blockIdx.z, s = z >> 4, b = z & 15;
  const void* srcv = (s == 0 ? in1 : (s == 1 ? in2 : in3));
  bool isbf = (*flag != 0);
  size_t base = (size_t)b * 524288;
  size_t dz = (size_t)z * 524288;
  int n0 = blockIdx.x * 32, c0 = blockIdx.y * 32;
  __shared__ bf16 t[32][33];
  int x = threadIdx.x & 31, y4 = (threadIdx.x >> 5) * 4;
#pragma unroll
  for (int i = 0; i < 4; i++) {
    size_t off = base + (size_t)(c0 + y4 + i) * 1024 + n0 + x;
    t[y4 + i][x] = isbf ? ((const bf16*)srcv)[off]
                        : __float2bfloat16(((const float*)srcv)[off]);
  }
  __syncthreads();
#pragma unroll
  for (int i = 0; i < 4; i++)
    dst[dz + (size_t)(n0 + y4 + i) * 512 + c0 + x] = t[x][y4 + i];
}

// ---------------- weight transform: [co][ci][3][3] -> [tap][co][ci] ---------
__global__ __launch_bounds__(256) void k_wtrans(const void* __restrict__ w,
                                                bf16* __restrict__ wT,
                                                const int* __restrict__ flag) {
  int idx = blockIdx.x * 256 + threadIdx.x;
  bool isbf = (*flag != 0);
#pragma unroll
  for (int t = 0; t < 9; t++) {
    bf16 v = isbf ? ((const bf16*)w)[(size_t)idx * 9 + t]
                  : __float2bfloat16(((const float*)w)[(size_t)idx * 9 + t]);
    wT[(size_t)t * 524288 + idx] = v;
  }
}

extern "C" void kernel_launch(void* const* d_in, const int* in_sizes, int n_in,
                              void* d_out, int out_size, void* d_ws, size_t ws_size,
                              hipStream_t stream) {
  (void)in_sizes; (void)n_in; (void)out_size; (void)ws_size;
  const void* in1 = d_in[0];
  const void* in2 = d_in[1];
  const void* in3 = d_in[2];

  char* ws = (char*)d_ws;
  bf16* state_h = (bf16*)(ws + 0);
  bf16* state_c = (bf16*)(ws + 50331648);
  bf16* AttA    = (bf16*)(ws + 100663296);
  bf16* RHbuf   = (bf16*)(ws + 100663296);
  bf16* in_nhwc = (bf16*)(ws + 100663296);
  bf16* AttB    = (bf16*)(ws + 150994944);
  bf16* Ubuf    = (bf16*)(ws + 150994944);
  bf16* OutTmp  = (bf16*)(ws + 150994944);
  float* Gbuf   = (float*)(ws + 201326592);
  bf16* Sbuf    = (bf16*)(ws + 201326592);   // in-place over G rows
  bf16* wT_out  = (bf16*)(ws + 201326592);   // after rounds only
  bf16* wT_fus  = (bf16*)(ws + 234881024);
  bf16* wR      = (bf16*)(ws + 244318208);
  bf16* wU      = (bf16*)(ws + 245366784);
  bf16* wC      = (bf16*)(ws + 246415360);
  bf16* bF      = (bf16*)(ws + 247463936);
  bf16* bO      = (bf16*)(ws + 247465984);
  bf16* bR      = (bf16*)(ws + 247468032);
  bf16* bU      = (bf16*)(ws + 247470080);
  bf16* bC      = (bf16*)(ws + 247472128);
  int*  flag    = (int*)(ws + 247474176);
  bf16* Abuf    = (bf16*)d_out;

  const size_t SLICE = 16 * 1024 * 512;   // elements per state slice
  const size_t CHUNK = 8 * 1024 * 512;    // elements per batch-chunk

  k_detect<<<1, 64, 0, stream>>>((const unsigned short*)d_in[0], flag);
  k_cvt<<<2048, 256, 0, stream>>>(d_in[7], wR, flag, 524288);
  k_cvt<<<2048, 256, 0, stream>>>(d_in[9], wU, flag, 524288);
  k_cvt<<<2048, 256, 0, stream>>>(d_in[11], wC, flag, 524288);
  k_cvt<<<2, 256, 0, stream>>>(d_in[4], bF, flag, 512);
  k_cvt<<<2, 256, 0, stream>>>(d_in[6], bO, flag, 512);
  k_cvt<<<2, 256, 0, stream>>>(d_in[8], bR, flag, 512);
  k_cvt<<<2, 256, 0, stream>>>(d_in[10], bU, flag, 512);
  k_cvt<<<2, 256, 0, stream>>>(d_in[12], bC, flag, 512);
  k_wtrans<<<2048, 256, 0, stream>>>(d_in[3], wT_fus, flag);
  k_init<<<dim3(32, 16, 48), 256, 0, stream>>>(in1, in2, in3, state_h, state_c, flag);

  const int sx[6] = {0, 0, 1, 1, 2, 2};
  const int sy[6] = {1, 2, 0, 2, 0, 1};
  for (int round = 0; round < 5; ++round) {
    for (int p = 0; p < 3; ++p) {
      for (int h = 0; h < 2; ++h) {
        int i = p * 2 + h;
        bf16* attdst = (h == 0 ? AttA : AttB) + p * SLICE;
        for (int cb = 0; cb < 2; ++cb) {
          size_t co = (size_t)cb * CHUNK;
          k_gram<<<dim3(8, 8, 8), 256, 0, stream>>>(
              state_h + sx[i] * SLICE + co, state_h + sy[i] * SLICE + co, Gbuf);
          k_softmax<<<8192, 256, 0, stream>>>(Gbuf);
          k_att<<<dim3(8, 4, 8), 256, 0, stream>>>(
              Sbuf, state_c + sy[i] * SLICE + co, attdst + co);
        }
      }
    }
    k_conv3<<<dim3(8, 4, 48), 256, 0, stream>>>(AttA, AttB, wT_fus, bF, Abuf);
    k_gru01<<<dim3(384, 8), 256, 0, stream>>>(Abuf, state_h, wR, bR, wU, bU,
                                              RHbuf, Ubuf);
    k_gru2<<<dim3(384, 4), 256, 0, stream>>>(Abuf, RHbuf, wC, bC, state_h, Ubuf);
    k_transpose<<<dim3(16, 32, 48), 256, 0, stream>>>(state_h, state_c, 1024, 512);
  }
  k_wtrans<<<2048, 256, 0, stream>>>(d_in[5], wT_out, flag);
  k_in_nhwc<<<dim3(32, 16, 48), 256, 0, stream>>>(in1, in2, in3, in_nhwc, flag);
  k_conv3<<<dim3(8, 4, 48), 256, 0, stream>>>(state_h, in_nhwc, wT_out, bO, OutTmp);
  k_store<<<dim3(16, 32, 48), 256, 0, stream>>>(OutTmp, d_out, flag);
}